// Round 18
// baseline (78.620 us; speedup 1.0000x reference)
//
#include <hip/hip_runtime.h>
#include <hip/hip_bf16.h>

#define BATCH 65536
#define INF   64
#define OUTF  256
#define NMAT  15
#define RPB   256          // rows per block
#define LDSW  36           // 32 cols + 4 pad floats

typedef __bf16 bf16x8 __attribute__((ext_vector_type(8)));
typedef float  f32x4  __attribute__((ext_vector_type(4)));

__device__ __forceinline__ unsigned short f2bf(float f) {
    unsigned int u = __float_as_uint(f);
    unsigned int r = (u + 0x7FFFu + ((u >> 16) & 1u)) >> 16;
    return (unsigned short)r;
}

// ---------------------------------------------------------------------------
// Weight layout (swizzled): per (mat w, 16-col strip cs):
//   byte = ((w*16+cs)*2+s)*1024 + lane*16   (lane = g*16+l15; k = s*32+g*8+j)
// slot order: 0=d1t, 1=d1_0, 2=M0, 3=d1_1, 4=M1, 5=M2, 6=d1_2, 7=M3, 8=M4,
// 9=M5, 10=d1_3, 11=M6, 12=M7, 13=M8, 14=M9  (M_p = dn_w2[p]*dn_w1[p][None,:])
// ---------------------------------------------------------------------------
__global__ void build_weights(const float* __restrict__ d1t_w,
                              const float* __restrict__ d1_w,
                              const float* __restrict__ dn_w1,
                              const float* __restrict__ dn_w2,
                              unsigned short* __restrict__ wcs) {
    const int idx = blockIdx.x * 256 + threadIdx.x;   // one 16-B chunk
    if (idx >= NMAT * OUTF * INF / 8) return;
    const signed char kind[NMAT] = {0,1,2,1,2,2,1,2,2,2,1,2,2,2,2};
    const signed char sidx[NMAT] = {0,0,0,1,1,2,2,3,4,5,3,6,7,8,9};
    const int slot = idx >> 11, rem8 = idx & 2047;
    const int o = rem8 >> 3, cc = rem8 & 7;
    const int s = cc >> 2, g = cc & 3;
    const int i0 = cc * 8;
    const int cs = o >> 4, l = o & 15;
    const int k = kind[slot], si = sidx[slot];
    unsigned short o8[8];
#pragma unroll
    for (int j = 0; j < 8; ++j) {
        const int e = o * INF + i0 + j;
        float v;
        if (k == 0)      v = d1t_w[e];
        else if (k == 1) v = d1_w[si * OUTF * INF + e];
        else             v = dn_w2[si * OUTF * INF + e] * dn_w1[si * INF + i0 + j];
        o8[j] = f2bf(v);
    }
    char* dst = (char*)wcs + (((size_t)slot * 16 + cs) * 2 + s) * 1024 + g * 256 + l * 16;
    *(bf16x8*)dst = *(bf16x8*)o8;
}

// R14/R16 compute structure, direct fp32 x, weight residency PINNED via asm
// (prevents the R15/R17 load-sinking failure), launch_bounds(256,3) for the
// extra transient-register headroom the in-loop cvt needs.
__global__ __launch_bounds__(256, 3) void taylor_kernel(
    const float* __restrict__ x, const float* __restrict__ d0w,
    const unsigned short* __restrict__ wcs, float* __restrict__ out)
{
    __shared__ float sbuf[2][2][32 * LDSW];   // 18 KB

    const int lane  = threadIdx.x & 63;
    const int wv    = threadIdx.x >> 6;   // 0..3
    const int strip = wv >> 1;            // 0..1
    const int role  = wv & 1;             // 0=A, 1=B
    const int l15   = lane & 15;
    const int g     = lane >> 4;
    // sharers of one row-chunk: bids {rc + 256k} -> all == rc mod 8 -> same XCD
    const int cg    = blockIdx.x >> 8;    // 32-col group (0..7)
    const int rc    = blockIdx.x & 255;   // row-chunk (256 rows)
    const int cs    = cg * 2 + strip;     // global 16-col strip id (0..15)

    // ---- weight prologue (role-split) --------------------------------------
    const int MA[8] = {0, 1, 2, 6, 7, 8, 9, 9};       // A uses first 7
    const int MB[8] = {3, 4, 5, 10, 11, 12, 13, 14};  // B uses all 8
    bf16x8 b[8][2];
    const char* wb0 = (const char*)wcs + lane * 16;
#pragma unroll
    for (int i = 0; i < 8; ++i) {
        const int m = role ? MB[i] : MA[i];
        if (role == 0 && i == 7) continue;            // A: only 7 mats
        const char* wp = wb0 + (((size_t)m * 16 + cs) * 2) * 1024;
        b[i][0] = *(const bf16x8*)(wp);
        b[i][1] = *(const bf16x8*)(wp + 1024);
    }
    // PIN weights in registers: asm redefines each value, so the compiler
    // cannot rematerialize (sink) the loads into the loop (R15/R17 failure).
#pragma unroll
    for (int i = 0; i < 8; ++i) {
        if (role == 0 && i == 7) continue;
        asm volatile("" : "+v"(b[i][0]), "+v"(b[i][1]));
    }
    const f32x4 d0v = *(const f32x4*)(d0w + cs * 16 + g * 4);

    const size_t row0 = (size_t)rc * RPB;

#pragma unroll
    for (int t = 0; t < 8; ++t) {
        // ---- fp32 x tile -> bf16 frags in-register -------------------------
        bf16x8 u00, u01, u10, u11;
        {
            const float* xp0 = x + (row0 + (size_t)t * 32 + l15) * INF + g * 8;
            const float* xp1 = xp0 + 16 * INF;
            f32x4 v0, v1; bf16x8 fr;
#define CVT8(dst, p0) { v0 = *(const f32x4*)(p0); v1 = *(const f32x4*)((p0) + 4); \
            _Pragma("unroll") \
            for (int j = 0; j < 4; ++j) { fr[j] = (__bf16)v0[j]; fr[4+j] = (__bf16)v1[j]; } dst = fr; }
            CVT8(u00, xp0); CVT8(u01, xp0 + 32); CVT8(u10, xp1); CVT8(u11, xp1 + 32);
#undef CVT8
        }

        f32x4 res0, res1, tmp0, tmp1, y0, y1;
        const f32x4 z = {0.f, 0.f, 0.f, 0.f};
        __builtin_amdgcn_s_setprio(1);
#define Y4(bi, c0)                                                                  \
        y0 = __builtin_amdgcn_mfma_f32_16x16x32_bf16(b[bi][0], u00, c0, 0, 0, 0);   \
        y1 = __builtin_amdgcn_mfma_f32_16x16x32_bf16(b[bi][0], u10, c0, 0, 0, 0);   \
        y0 = __builtin_amdgcn_mfma_f32_16x16x32_bf16(b[bi][1], u01, y0, 0, 0, 0);   \
        y1 = __builtin_amdgcn_mfma_f32_16x16x32_bf16(b[bi][1], u11, y1, 0, 0, 0);
        if (role == 0) {
            Y4(0, d0v) res0 = y0; res1 = y1;                      // d1t (+d0)
            Y4(1, z)   tmp0 = y0; tmp1 = y1;                      // T1
            Y4(2, z)   tmp0 *= y0; tmp1 *= y1; res0 += tmp0; res1 += tmp1;
            Y4(3, z)   tmp0 = y0; tmp1 = y1;                      // T3
            Y4(4, z)   tmp0 *= y0; tmp1 *= y1;
            Y4(5, z)   tmp0 *= y0; tmp1 *= y1;
            Y4(6, z)   tmp0 *= y0; tmp1 *= y1; res0 += tmp0; res1 += tmp1;
        } else {
            Y4(0, z)   tmp0 = y0; tmp1 = y1;                      // T2
            Y4(1, z)   tmp0 *= y0; tmp1 *= y1;
            Y4(2, z)   tmp0 *= y0; tmp1 *= y1; res0 = tmp0; res1 = tmp1;
            Y4(3, z)   tmp0 = y0; tmp1 = y1;                      // T4
            Y4(4, z)   tmp0 *= y0; tmp1 *= y1;
            Y4(5, z)   tmp0 *= y0; tmp1 *= y1;
            Y4(6, z)   tmp0 *= y0; tmp1 *= y1;
            Y4(7, z)   tmp0 *= y0; tmp1 *= y1; res0 += tmp0; res1 += tmp1;
        }
#undef Y4
        __builtin_amdgcn_s_setprio(0);

        // ---- partials -> LDS -----------------------------------------------
        float* sb = &sbuf[t & 1][role][0];
        const int colw = strip * 16 + g * 4;
        *(f32x4*)&sb[l15 * LDSW + colw]        = res0;
        *(f32x4*)&sb[(16 + l15) * LDSW + colw] = res1;
        // lgkm-only barrier: VMEM stays in flight (proven R11/R14/R16).
        asm volatile("s_waitcnt lgkmcnt(0)\n\ts_barrier" ::: "memory");

        // ---- store: A+B, full 128-B lines over the 32-col swath ------------
        const float* pA = &sbuf[t & 1][0][0];
        const float* pB = &sbuf[t & 1][1][0];
        const int rr = threadIdx.x >> 3;          // 0..31
        const int c4 = (threadIdx.x & 7) * 4;     // 0..28
        f32x4 v = *(const f32x4*)&pA[rr * LDSW + c4];
        v = v + *(const f32x4*)&pB[rr * LDSW + c4];
        *(f32x4*)(out + (row0 + (size_t)t * 32 + rr) * OUTF + cg * 32 + c4) = v;
    }
}

extern "C" void kernel_launch(void* const* d_in, const int* in_sizes, int n_in,
                              void* d_out, int out_size, void* d_ws, size_t ws_size,
                              hipStream_t stream) {
    const float* x    = (const float*)d_in[0];
    const float* d0   = (const float*)d_in[1];
    const float* d1t  = (const float*)d_in[2];
    const float* d1w  = (const float*)d_in[3];
    const float* dnw1 = (const float*)d_in[4];
    const float* dnw2 = (const float*)d_in[5];
    unsigned short* wcs = (unsigned short*)d_ws;   // 480 KiB swizzled weights
    float* out = (float*)d_out;

    build_weights<<<(NMAT * OUTF * INF / 8 + 255) / 256, 256, 0, stream>>>(
        d1t, d1w, dnw1, dnw2, wcs);
    taylor_kernel<<<8 * (BATCH / RPB), 256, 0, stream>>>(x, d0, wcs, out);
}

// Round 19
// 42.171 us; speedup vs baseline: 1.8643x; 1.8643x over previous
//
#include <hip/hip_runtime.h>
#include <hip/hip_bf16.h>

#define BATCH 65536
#define INF   64
#define OUTF  256
#define NMAT  15
#define RPB   256          // rows per block
#define LDSW  36           // 32 cols + 4 pad floats

typedef __bf16 bf16x8 __attribute__((ext_vector_type(8)));
typedef float  f32x4  __attribute__((ext_vector_type(4)));

__device__ __forceinline__ unsigned short f2bf(float f) {
    unsigned int u = __float_as_uint(f);
    unsigned int r = (u + 0x7FFFu + ((u >> 16) & 1u)) >> 16;
    return (unsigned short)r;
}

// Opaque weight load: asm-produced value cannot be rematerialized/sunk by the
// compiler, guaranteeing register residency across the tile loop (the R15/R17/
// R18 silent-reload failure mode is structurally impossible).
__device__ __forceinline__ void wload(bf16x8& d, const void* p) {
    asm volatile("global_load_dwordx4 %0, %1, off" : "=v"(d) : "v"(p));
}

// ---------------------------------------------------------------------------
// Layouts (proven):
//   xs:  per 16-row group grp: byte = grp*2048 + s*1024 + lane*16
//        (lane = g*16 + r, r = row&15, k = s*32 + g*8 + j)
//   wcs: per (mat w, 16-col strip cs): byte = ((w*16+cs)*2+s)*1024 + lane*16
// ---------------------------------------------------------------------------
__global__ void prep(const float* __restrict__ x,
                     const float* __restrict__ d1t_w,
                     const float* __restrict__ d1_w,
                     const float* __restrict__ dn_w1,
                     const float* __restrict__ dn_w2,
                     unsigned short* __restrict__ wcs,
                     unsigned short* __restrict__ xs) {
    const int idx = blockIdx.x * 256 + threadIdx.x;   // one 16-B chunk each

    {   // x: chunk idx covers row = idx>>3, elems cc*8..cc*8+7
        const int row = idx >> 3, cc = idx & 7;
        const int s = cc >> 2, g = cc & 3;
        const int grp = row >> 4, r = row & 15;
        const float* xp = x + (size_t)row * INF + cc * 8;
        f32x4 v0 = *(const f32x4*)xp;
        f32x4 v1 = *(const f32x4*)(xp + 4);
        bf16x8 fr;
#pragma unroll
        for (int j = 0; j < 4; ++j) { fr[j] = (__bf16)v0[j]; fr[4 + j] = (__bf16)v1[j]; }
        *(bf16x8*)((char*)xs + (size_t)grp * 2048 + s * 1024 + g * 256 + r * 16) = fr;
    }

    if (idx < NMAT * OUTF * INF / 8) {
        const signed char kind[NMAT] = {0,1,2,1,2,2,1,2,2,2,1,2,2,2,2};
        const signed char sidx[NMAT] = {0,0,0,1,1,2,2,3,4,5,3,6,7,8,9};
        const int slot = idx >> 11, rem8 = idx & 2047;
        const int o = rem8 >> 3, cc = rem8 & 7;
        const int s = cc >> 2, g = cc & 3;
        const int i0 = cc * 8;
        const int cs = o >> 4, l = o & 15;
        const int k = kind[slot], si = sidx[slot];
        unsigned short o8[8];
#pragma unroll
        for (int j = 0; j < 8; ++j) {
            const int e = o * INF + i0 + j;
            float v;
            if (k == 0)      v = d1t_w[e];
            else if (k == 1) v = d1_w[si * OUTF * INF + e];
            else             v = dn_w2[si * OUTF * INF + e] * dn_w1[si * INF + i0 + j];
            o8[j] = f2bf(v);
        }
        char* dst = (char*)wcs + (((size_t)slot * 16 + cs) * 2 + s) * 1024 + g * 256 + l * 16;
        *(bf16x8*)dst = *(bf16x8*)o8;
    }
}

// R16 structure with GUARANTEED weight residency (asm loads). Role A: 7 mats,
// role B: 8 mats; partials combine in LDS; full 128-B-line stores.
__global__ __launch_bounds__(256, 3) void taylor_kernel(
    const unsigned short* __restrict__ xs, const float* __restrict__ d0w,
    const unsigned short* __restrict__ wcs, float* __restrict__ out)
{
    __shared__ float sbuf[2][2][32 * LDSW];   // 18 KB

    const int lane  = threadIdx.x & 63;
    const int wv    = threadIdx.x >> 6;   // 0..3
    const int strip = wv >> 1;            // 0..1
    const int role  = wv & 1;             // 0=A, 1=B
    const int l15   = lane & 15;
    const int g     = lane >> 4;
    // sharers of one row-chunk: bids {rc + 256k} -> all == rc mod 8 -> same XCD
    const int cg    = blockIdx.x >> 8;    // 32-col group (0..7)
    const int rc    = blockIdx.x & 255;   // row-chunk (256 rows)
    const int cs    = cg * 2 + strip;     // global 16-col strip id (0..15)

    // ---- weight prologue: opaque asm loads (residency-guaranteed) ----------
    const int MA[8] = {0, 1, 2, 6, 7, 8, 9, 9};       // A uses first 7
    const int MB[8] = {3, 4, 5, 10, 11, 12, 13, 14};  // B uses all 8
    bf16x8 b[8][2];
    const char* wb0 = (const char*)wcs + lane * 16;
#pragma unroll
    for (int i = 0; i < 8; ++i) {
        const int m = role ? MB[i] : MA[i];
        if (role == 0 && i == 7) continue;            // A: only 7 mats
        const char* wp = wb0 + (((size_t)m * 16 + cs) * 2) * 1024;
        wload(b[i][0], wp);
        wload(b[i][1], wp + 1024);
    }
    // drain the asm loads; sched_barrier stops register-only MFMAs from being
    // hoisted above the wait (rule #18 analog for vmcnt).
    asm volatile("s_waitcnt vmcnt(0)" ::: "memory");
    __builtin_amdgcn_sched_barrier(0);

    const f32x4 d0v = *(const f32x4*)(d0w + cs * 16 + g * 4);

    const size_t row0 = (size_t)rc * RPB;
    const char* xbase = (const char*)xs + (row0 >> 4) * 2048 + lane * 16;

    // prologue: tile 0
    bf16x8 u00 = *(const bf16x8*)(xbase);
    bf16x8 u01 = *(const bf16x8*)(xbase + 1024);
    bf16x8 u10 = *(const bf16x8*)(xbase + 2048);
    bf16x8 u11 = *(const bf16x8*)(xbase + 3072);

#pragma unroll
    for (int t = 0; t < 8; ++t) {
        f32x4 res0, res1, tmp0, tmp1, y0, y1;
        const f32x4 z = {0.f, 0.f, 0.f, 0.f};
        __builtin_amdgcn_s_setprio(1);
#define Y4(bi, c0)                                                                  \
        y0 = __builtin_amdgcn_mfma_f32_16x16x32_bf16(b[bi][0], u00, c0, 0, 0, 0);   \
        y1 = __builtin_amdgcn_mfma_f32_16x16x32_bf16(b[bi][0], u10, c0, 0, 0, 0);   \
        y0 = __builtin_amdgcn_mfma_f32_16x16x32_bf16(b[bi][1], u01, y0, 0, 0, 0);   \
        y1 = __builtin_amdgcn_mfma_f32_16x16x32_bf16(b[bi][1], u11, y1, 0, 0, 0);
        if (role == 0) {
            Y4(0, d0v) res0 = y0; res1 = y1;                      // d1t (+d0)
            Y4(1, z)   tmp0 = y0; tmp1 = y1;                      // T1
            Y4(2, z)   tmp0 *= y0; tmp1 *= y1; res0 += tmp0; res1 += tmp1;
            Y4(3, z)   tmp0 = y0; tmp1 = y1;                      // T3
            Y4(4, z)   tmp0 *= y0; tmp1 *= y1;
            Y4(5, z)   tmp0 *= y0; tmp1 *= y1;
            Y4(6, z)   tmp0 *= y0; tmp1 *= y1; res0 += tmp0; res1 += tmp1;
        } else {
            Y4(0, z)   tmp0 = y0; tmp1 = y1;                      // T2
            Y4(1, z)   tmp0 *= y0; tmp1 *= y1;
            Y4(2, z)   tmp0 *= y0; tmp1 *= y1; res0 = tmp0; res1 = tmp1;
            Y4(3, z)   tmp0 = y0; tmp1 = y1;                      // T4
            Y4(4, z)   tmp0 *= y0; tmp1 *= y1;
            Y4(5, z)   tmp0 *= y0; tmp1 *= y1;
            Y4(6, z)   tmp0 *= y0; tmp1 *= y1;
            Y4(7, z)   tmp0 *= y0; tmp1 *= y1; res0 += tmp0; res1 += tmp1;
        }
#undef Y4
        __builtin_amdgcn_s_setprio(0);

        // ---- pipelined load of tile t+1 into the same regs (WAR-ordered) ---
        if (t < 7) {
            const char* p = xbase + (size_t)(t + 1) * 4096;
            u00 = *(const bf16x8*)(p);
            u01 = *(const bf16x8*)(p + 1024);
            u10 = *(const bf16x8*)(p + 2048);
            u11 = *(const bf16x8*)(p + 3072);
        }

        // ---- partials -> LDS -----------------------------------------------
        float* sb = &sbuf[t & 1][role][0];
        const int colw = strip * 16 + g * 4;
        *(f32x4*)&sb[l15 * LDSW + colw]        = res0;
        *(f32x4*)&sb[(16 + l15) * LDSW + colw] = res1;
        // lgkm-only barrier: VMEM stays in flight (proven R11/R14/R16).
        asm volatile("s_waitcnt lgkmcnt(0)\n\ts_barrier" ::: "memory");

        // ---- store: A+B, full 128-B lines over the 32-col swath ------------
        const float* pA = &sbuf[t & 1][0][0];
        const float* pB = &sbuf[t & 1][1][0];
        const int rr = threadIdx.x >> 3;          // 0..31
        const int c4 = (threadIdx.x & 7) * 4;     // 0..28
        f32x4 v = *(const f32x4*)&pA[rr * LDSW + c4];
        v = v + *(const f32x4*)&pB[rr * LDSW + c4];
        *(f32x4*)(out + (row0 + (size_t)t * 32 + rr) * OUTF + cg * 32 + c4) = v;
    }
}

// ---------------- fallback path (ws too small): R6-style fp32 kernel --------
__global__ void build_weights_only(const float* __restrict__ d1t_w,
                                   const float* __restrict__ d1_w,
                                   const float* __restrict__ dn_w1,
                                   const float* __restrict__ dn_w2,
                                   unsigned short* __restrict__ wc) {
    int idx = blockIdx.x * blockDim.x + threadIdx.x;
    if (idx >= NMAT * OUTF * INF) return;
    int slot = idx / (OUTF * INF);
    int rem  = idx - slot * (OUTF * INF);
    int i    = rem & (INF - 1);
    const signed char kind[NMAT] = {0,1,2,1,2,2,1,2,2,2,1,2,2,2,2};
    const signed char sidx[NMAT] = {0,0,0,1,1,2,2,3,4,5,3,6,7,8,9};
    int k = kind[slot], si = sidx[slot];
    float v;
    if (k == 0)      v = d1t_w[rem];
    else if (k == 1) v = d1_w[si * OUTF * INF + rem];
    else             v = dn_w2[si * OUTF * INF + rem] * dn_w1[si * INF + i];
    wc[idx] = f2bf(v);
}

__global__ __launch_bounds__(256) void taylor_f32(
    const float* __restrict__ x, const float* __restrict__ d0,
    const unsigned short* __restrict__ wc, float* __restrict__ out)
{
    const int lane = threadIdx.x & 63;
    const int wave = threadIdx.x >> 6;
    const int l15  = lane & 15;
    const int g    = lane >> 4;
    const int cg   = blockIdx.x & 3;
    const int rc   = blockIdx.x >> 2;
    const int colstrip = cg * 64 + wave * 16;

    bf16x8 b[NMAT][2];
#pragma unroll
    for (int w = 0; w < NMAT; ++w) {
        const unsigned short* wp = wc + ((size_t)w * OUTF + colstrip + l15) * INF + g * 8;
#pragma unroll
        for (int s = 0; s < 2; ++s)
            b[w][s] = *(const bf16x8*)(wp + s * 32);
    }
    const f32x4 d0v = *(const f32x4*)(d0 + colstrip + g * 4);
    constexpr int OPS[NMAT] = {0,1,3,1,2,3,1,2,2,3,1,2,2,2,3};
    const size_t row0 = (size_t)rc * RPB;

#pragma unroll 1
    for (int it = 0; it < RPB / 32; ++it) {
        bf16x8 a00, a01, a10, a11;
        {
            const float* xp0 = x + (row0 + (size_t)it * 32 + l15) * INF + g * 8;
            const float* xp1 = xp0 + 16 * INF;
            f32x4 u0, u1; bf16x8 fr;
#define CVT8(dst, p0) { u0 = *(const f32x4*)(p0); u1 = *(const f32x4*)((p0) + 4); \
            for (int j = 0; j < 4; ++j) { fr[j] = (__bf16)u0[j]; fr[4+j] = (__bf16)u1[j]; } dst = fr; }
            CVT8(a00, xp0); CVT8(a01, xp0 + 32); CVT8(a10, xp1); CVT8(a11, xp1 + 32);
#undef CVT8
        }
        f32x4 res0, res1, tmp0, tmp1;
#pragma unroll
        for (int w = 0; w < NMAT; ++w) {
            f32x4 c0 = (OPS[w] == 0) ? d0v : f32x4{0.f, 0.f, 0.f, 0.f};
            f32x4 y0 = __builtin_amdgcn_mfma_f32_16x16x32_bf16(b[w][0], a00, c0, 0, 0, 0);
            y0       = __builtin_amdgcn_mfma_f32_16x16x32_bf16(b[w][1], a01, y0, 0, 0, 0);
            f32x4 y1 = __builtin_amdgcn_mfma_f32_16x16x32_bf16(b[w][0], a10, c0, 0, 0, 0);
            y1       = __builtin_amdgcn_mfma_f32_16x16x32_bf16(b[w][1], a11, y1, 0, 0, 0);
            if (OPS[w] == 0)      { res0 = y0; res1 = y1; }
            else if (OPS[w] == 1) { tmp0 = y0; tmp1 = y1; }
            else {
                tmp0 = tmp0 * y0; tmp1 = tmp1 * y1;
                if (OPS[w] == 3) { res0 = res0 + tmp0; res1 = res1 + tmp1; }
            }
        }
        const size_t rbase = row0 + (size_t)it * 32;
        *(f32x4*)(out + (rbase + l15) * OUTF + colstrip + g * 4) = res0;
        *(f32x4*)(out + (rbase + 16 + l15) * OUTF + colstrip + g * 4) = res1;
    }
}

extern "C" void kernel_launch(void* const* d_in, const int* in_sizes, int n_in,
                              void* d_out, int out_size, void* d_ws, size_t ws_size,
                              hipStream_t stream) {
    const float* x    = (const float*)d_in[0];
    const float* d0   = (const float*)d_in[1];
    const float* d1t  = (const float*)d_in[2];
    const float* d1w  = (const float*)d_in[3];
    const float* dnw1 = (const float*)d_in[4];
    const float* dnw2 = (const float*)d_in[5];
    unsigned short* wc = (unsigned short*)d_ws;                 // 480 KiB (swizzled)
    float* out = (float*)d_out;

    const size_t XB_OFF   = 512 * 1024;
    const size_t XB_BYTES = (size_t)BATCH * INF * 2;            // 8 MiB
    if (ws_size >= XB_OFF + XB_BYTES) {
        unsigned short* xs = (unsigned short*)((char*)d_ws + XB_OFF);
        prep<<<BATCH * INF / 8 / 256, 256, 0, stream>>>(x, d1t, d1w, dnw1, dnw2, wc, xs);
        taylor_kernel<<<8 * (BATCH / RPB), 256, 0, stream>>>(xs, d0, wc, out);
    } else {
        build_weights_only<<<(NMAT * OUTF * INF + 255) / 256, 256, 0, stream>>>(d1t, d1w, dnw1, dnw2, wc);
        taylor_f32<<<4 * (BATCH / RPB), 256, 0, stream>>>(x, d0, wc, out);
    }
}

// Round 20
// 41.316 us; speedup vs baseline: 1.9029x; 1.0207x over previous
//
#include <hip/hip_runtime.h>
#include <hip/hip_bf16.h>

#define BATCH 65536
#define INF   64
#define OUTF  256
#define NMAT  15
#define RPB   256          // rows per block
#define LDSW  36           // 32 cols + 4 pad floats

typedef __bf16 bf16x8 __attribute__((ext_vector_type(8)));
typedef float  f32x4  __attribute__((ext_vector_type(4)));

__device__ __forceinline__ unsigned short f2bf(float f) {
    unsigned int u = __float_as_uint(f);
    unsigned int r = (u + 0x7FFFu + ((u >> 16) & 1u)) >> 16;
    return (unsigned short)r;
}

// Opaque weight load: asm-produced value cannot be rematerialized/sunk by the
// compiler, guaranteeing register residency across the tile loop.
__device__ __forceinline__ void wload(bf16x8& d, const void* p) {
    asm volatile("global_load_dwordx4 %0, %1, off" : "=v"(d) : "v"(p));
}

// ---------------------------------------------------------------------------
// Layouts (proven):
//   xs:  per 16-row group grp: byte = grp*2048 + s*1024 + lane*16
//        (lane = g*16 + r, r = row&15, k = s*32 + g*8 + j)
//   wcs: per (mat w, 16-col strip cs): byte = ((w*16+cs)*2+s)*1024 + lane*16
// ---------------------------------------------------------------------------
__global__ void prep(const float* __restrict__ x,
                     const float* __restrict__ d1t_w,
                     const float* __restrict__ d1_w,
                     const float* __restrict__ dn_w1,
                     const float* __restrict__ dn_w2,
                     unsigned short* __restrict__ wcs,
                     unsigned short* __restrict__ xs) {
    const int idx = blockIdx.x * 256 + threadIdx.x;   // one 16-B chunk each

    {   // x: chunk idx covers row = idx>>3, elems cc*8..cc*8+7
        const int row = idx >> 3, cc = idx & 7;
        const int s = cc >> 2, g = cc & 3;
        const int grp = row >> 4, r = row & 15;
        const float* xp = x + (size_t)row * INF + cc * 8;
        f32x4 v0 = *(const f32x4*)xp;
        f32x4 v1 = *(const f32x4*)(xp + 4);
        bf16x8 fr;
#pragma unroll
        for (int j = 0; j < 4; ++j) { fr[j] = (__bf16)v0[j]; fr[4 + j] = (__bf16)v1[j]; }
        *(bf16x8*)((char*)xs + (size_t)grp * 2048 + s * 1024 + g * 256 + r * 16) = fr;
    }

    if (idx < NMAT * OUTF * INF / 8) {
        const signed char kind[NMAT] = {0,1,2,1,2,2,1,2,2,2,1,2,2,2,2};
        const signed char sidx[NMAT] = {0,0,0,1,1,2,2,3,4,5,3,6,7,8,9};
        const int slot = idx >> 11, rem8 = idx & 2047;
        const int o = rem8 >> 3, cc = rem8 & 7;
        const int s = cc >> 2, g = cc & 3;
        const int i0 = cc * 8;
        const int cs = o >> 4, l = o & 15;
        const int k = kind[slot], si = sidx[slot];
        unsigned short o8[8];
#pragma unroll
        for (int j = 0; j < 8; ++j) {
            const int e = o * INF + i0 + j;
            float v;
            if (k == 0)      v = d1t_w[e];
            else if (k == 1) v = d1_w[si * OUTF * INF + e];
            else             v = dn_w2[si * OUTF * INF + e] * dn_w1[si * INF + i0 + j];
            o8[j] = f2bf(v);
        }
        char* dst = (char*)wcs + (((size_t)slot * 16 + cs) * 2 + s) * 1024 + g * 256 + l * 16;
        *(bf16x8*)dst = *(bf16x8*)o8;
    }
}

// R19 structure + NONTEMPORAL full-line output stores: stores bypass L2
// (no eviction pressure on xs/weights, no write-back serialization). Safe
// now because each 8-lane group writes an exact, aligned 128-B line
// (R5's NT regression was partial 64-B segments -> RMW amplification).
__global__ __launch_bounds__(256, 3) void taylor_kernel(
    const unsigned short* __restrict__ xs, const float* __restrict__ d0w,
    const unsigned short* __restrict__ wcs, float* __restrict__ out)
{
    __shared__ float sbuf[2][2][32 * LDSW];   // 18 KB

    const int lane  = threadIdx.x & 63;
    const int wv    = threadIdx.x >> 6;   // 0..3
    const int strip = wv >> 1;            // 0..1
    const int role  = wv & 1;             // 0=A, 1=B
    const int l15   = lane & 15;
    const int g     = lane >> 4;
    // sharers of one row-chunk: bids {rc + 256k} -> all == rc mod 8 -> same XCD
    const int cg    = blockIdx.x >> 8;    // 32-col group (0..7)
    const int rc    = blockIdx.x & 255;   // row-chunk (256 rows)
    const int cs    = cg * 2 + strip;     // global 16-col strip id (0..15)

    // ---- weight prologue: opaque asm loads (residency-guaranteed) ----------
    const int MA[8] = {0, 1, 2, 6, 7, 8, 9, 9};       // A uses first 7
    const int MB[8] = {3, 4, 5, 10, 11, 12, 13, 14};  // B uses all 8
    bf16x8 b[8][2];
    const char* wb0 = (const char*)wcs + lane * 16;
#pragma unroll
    for (int i = 0; i < 8; ++i) {
        const int m = role ? MB[i] : MA[i];
        if (role == 0 && i == 7) continue;            // A: only 7 mats
        const char* wp = wb0 + (((size_t)m * 16 + cs) * 2) * 1024;
        wload(b[i][0], wp);
        wload(b[i][1], wp + 1024);
    }
    asm volatile("s_waitcnt vmcnt(0)" ::: "memory");
    __builtin_amdgcn_sched_barrier(0);

    const f32x4 d0v = *(const f32x4*)(d0w + cs * 16 + g * 4);

    const size_t row0 = (size_t)rc * RPB;
    const char* xbase = (const char*)xs + (row0 >> 4) * 2048 + lane * 16;

    // prologue: tile 0
    bf16x8 u00 = *(const bf16x8*)(xbase);
    bf16x8 u01 = *(const bf16x8*)(xbase + 1024);
    bf16x8 u10 = *(const bf16x8*)(xbase + 2048);
    bf16x8 u11 = *(const bf16x8*)(xbase + 3072);

#pragma unroll
    for (int t = 0; t < 8; ++t) {
        f32x4 res0, res1, tmp0, tmp1, y0, y1;
        const f32x4 z = {0.f, 0.f, 0.f, 0.f};
        __builtin_amdgcn_s_setprio(1);
#define Y4(bi, c0)                                                                  \
        y0 = __builtin_amdgcn_mfma_f32_16x16x32_bf16(b[bi][0], u00, c0, 0, 0, 0);   \
        y1 = __builtin_amdgcn_mfma_f32_16x16x32_bf16(b[bi][0], u10, c0, 0, 0, 0);   \
        y0 = __builtin_amdgcn_mfma_f32_16x16x32_bf16(b[bi][1], u01, y0, 0, 0, 0);   \
        y1 = __builtin_amdgcn_mfma_f32_16x16x32_bf16(b[bi][1], u11, y1, 0, 0, 0);
        if (role == 0) {
            Y4(0, d0v) res0 = y0; res1 = y1;                      // d1t (+d0)
            Y4(1, z)   tmp0 = y0; tmp1 = y1;                      // T1
            Y4(2, z)   tmp0 *= y0; tmp1 *= y1; res0 += tmp0; res1 += tmp1;
            Y4(3, z)   tmp0 = y0; tmp1 = y1;                      // T3
            Y4(4, z)   tmp0 *= y0; tmp1 *= y1;
            Y4(5, z)   tmp0 *= y0; tmp1 *= y1;
            Y4(6, z)   tmp0 *= y0; tmp1 *= y1; res0 += tmp0; res1 += tmp1;
        } else {
            Y4(0, z)   tmp0 = y0; tmp1 = y1;                      // T2
            Y4(1, z)   tmp0 *= y0; tmp1 *= y1;
            Y4(2, z)   tmp0 *= y0; tmp1 *= y1; res0 = tmp0; res1 = tmp1;
            Y4(3, z)   tmp0 = y0; tmp1 = y1;                      // T4
            Y4(4, z)   tmp0 *= y0; tmp1 *= y1;
            Y4(5, z)   tmp0 *= y0; tmp1 *= y1;
            Y4(6, z)   tmp0 *= y0; tmp1 *= y1;
            Y4(7, z)   tmp0 *= y0; tmp1 *= y1; res0 += tmp0; res1 += tmp1;
        }
#undef Y4
        __builtin_amdgcn_s_setprio(0);

        // ---- pipelined load of tile t+1 into the same regs (WAR-ordered) ---
        if (t < 7) {
            const char* p = xbase + (size_t)(t + 1) * 4096;
            u00 = *(const bf16x8*)(p);
            u01 = *(const bf16x8*)(p + 1024);
            u10 = *(const bf16x8*)(p + 2048);
            u11 = *(const bf16x8*)(p + 3072);
        }

        // ---- partials -> LDS -----------------------------------------------
        float* sb = &sbuf[t & 1][role][0];
        const int colw = strip * 16 + g * 4;
        *(f32x4*)&sb[l15 * LDSW + colw]        = res0;
        *(f32x4*)&sb[(16 + l15) * LDSW + colw] = res1;
        // lgkm-only barrier: VMEM stays in flight (proven R11/R14/R16).
        asm volatile("s_waitcnt lgkmcnt(0)\n\ts_barrier" ::: "memory");

        // ---- store: A+B, nontemporal full 128-B lines (bypass L2) ----------
        const float* pA = &sbuf[t & 1][0][0];
        const float* pB = &sbuf[t & 1][1][0];
        const int rr = threadIdx.x >> 3;          // 0..31
        const int c4 = (threadIdx.x & 7) * 4;     // 0..28
        f32x4 v = *(const f32x4*)&pA[rr * LDSW + c4];
        v = v + *(const f32x4*)&pB[rr * LDSW + c4];
        float* op = out + (row0 + (size_t)t * 32 + rr) * OUTF + cg * 32 + c4;
        __builtin_nontemporal_store(v, (f32x4*)op);
    }
}

// ---------------- fallback path (ws too small): R6-style fp32 kernel --------
__global__ void build_weights_only(const float* __restrict__ d1t_w,
                                   const float* __restrict__ d1_w,
                                   const float* __restrict__ dn_w1,
                                   const float* __restrict__ dn_w2,
                                   unsigned short* __restrict__ wc) {
    int idx = blockIdx.x * blockDim.x + threadIdx.x;
    if (idx >= NMAT * OUTF * INF) return;
    int slot = idx / (OUTF * INF);
    int rem  = idx - slot * (OUTF * INF);
    int i    = rem & (INF - 1);
    const signed char kind[NMAT] = {0,1,2,1,2,2,1,2,2,2,1,2,2,2,2};
    const signed char sidx[NMAT] = {0,0,0,1,1,2,2,3,4,5,3,6,7,8,9};
    int k = kind[slot], si = sidx[slot];
    float v;
    if (k == 0)      v = d1t_w[rem];
    else if (k == 1) v = d1_w[si * OUTF * INF + rem];
    else             v = dn_w2[si * OUTF * INF + rem] * dn_w1[si * INF + i];
    wc[idx] = f2bf(v);
}

__global__ __launch_bounds__(256) void taylor_f32(
    const float* __restrict__ x, const float* __restrict__ d0,
    const unsigned short* __restrict__ wc, float* __restrict__ out)
{
    const int lane = threadIdx.x & 63;
    const int wave = threadIdx.x >> 6;
    const int l15  = lane & 15;
    const int g    = lane >> 4;
    const int cg   = blockIdx.x & 3;
    const int rc   = blockIdx.x >> 2;
    const int colstrip = cg * 64 + wave * 16;

    bf16x8 b[NMAT][2];
#pragma unroll
    for (int w = 0; w < NMAT; ++w) {
        const unsigned short* wp = wc + ((size_t)w * OUTF + colstrip + l15) * INF + g * 8;
#pragma unroll
        for (int s = 0; s < 2; ++s)
            b[w][s] = *(const bf16x8*)(wp + s * 32);
    }
    const f32x4 d0v = *(const f32x4*)(d0 + colstrip + g * 4);
    constexpr int OPS[NMAT] = {0,1,3,1,2,3,1,2,2,3,1,2,2,2,3};
    const size_t row0 = (size_t)rc * RPB;

#pragma unroll 1
    for (int it = 0; it < RPB / 32; ++it) {
        bf16x8 a00, a01, a10, a11;
        {
            const float* xp0 = x + (row0 + (size_t)it * 32 + l15) * INF + g * 8;
            const float* xp1 = xp0 + 16 * INF;
            f32x4 u0, u1; bf16x8 fr;
#define CVT8(dst, p0) { u0 = *(const f32x4*)(p0); u1 = *(const f32x4*)((p0) + 4); \
            for (int j = 0; j < 4; ++j) { fr[j] = (__bf16)u0[j]; fr[4+j] = (__bf16)u1[j]; } dst = fr; }
            CVT8(a00, xp0); CVT8(a01, xp0 + 32); CVT8(a10, xp1); CVT8(a11, xp1 + 32);
#undef CVT8
        }
        f32x4 res0, res1, tmp0, tmp1;
#pragma unroll
        for (int w = 0; w < NMAT; ++w) {
            f32x4 c0 = (OPS[w] == 0) ? d0v : f32x4{0.f, 0.f, 0.f, 0.f};
            f32x4 y0 = __builtin_amdgcn_mfma_f32_16x16x32_bf16(b[w][0], a00, c0, 0, 0, 0);
            y0       = __builtin_amdgcn_mfma_f32_16x16x32_bf16(b[w][1], a01, y0, 0, 0, 0);
            f32x4 y1 = __builtin_amdgcn_mfma_f32_16x16x32_bf16(b[w][0], a10, c0, 0, 0, 0);
            y1       = __builtin_amdgcn_mfma_f32_16x16x32_bf16(b[w][1], a11, y1, 0, 0, 0);
            if (OPS[w] == 0)      { res0 = y0; res1 = y1; }
            else if (OPS[w] == 1) { tmp0 = y0; tmp1 = y1; }
            else {
                tmp0 = tmp0 * y0; tmp1 = tmp1 * y1;
                if (OPS[w] == 3) { res0 = res0 + tmp0; res1 = res1 + tmp1; }
            }
        }
        const size_t rbase = row0 + (size_t)it * 32;
        *(f32x4*)(out + (rbase + l15) * OUTF + colstrip + g * 4) = res0;
        *(f32x4*)(out + (rbase + 16 + l15) * OUTF + colstrip + g * 4) = res1;
    }
}

extern "C" void kernel_launch(void* const* d_in, const int* in_sizes, int n_in,
                              void* d_out, int out_size, void* d_ws, size_t ws_size,
                              hipStream_t stream) {
    const float* x    = (const float*)d_in[0];
    const float* d0   = (const float*)d_in[1];
    const float* d1t  = (const float*)d_in[2];
    const float* d1w  = (const float*)d_in[3];
    const float* dnw1 = (const float*)d_in[4];
    const float* dnw2 = (const float*)d_in[5];
    unsigned short* wc = (unsigned short*)d_ws;                 // 480 KiB (swizzled)
    float* out = (float*)d_out;

    const size_t XB_OFF   = 512 * 1024;
    const size_t XB_BYTES = (size_t)BATCH * INF * 2;            // 8 MiB
    if (ws_size >= XB_OFF + XB_BYTES) {
        unsigned short* xs = (unsigned short*)((char*)d_ws + XB_OFF);
        prep<<<BATCH * INF / 8 / 256, 256, 0, stream>>>(x, d1t, d1w, dnw1, dnw2, wc, xs);
        taylor_kernel<<<8 * (BATCH / RPB), 256, 0, stream>>>(xs, d0, wc, out);
    } else {
        build_weights_only<<<(NMAT * OUTF * INF + 255) / 256, 256, 0, stream>>>(d1t, d1w, dnw1, dnw2, wc);
        taylor_f32<<<4 * (BATCH / RPB), 256, 0, stream>>>(x, d0, wc, out);
    }
}